// Round 4
// baseline (651.156 us; speedup 1.0000x reference)
//
#include <hip/hip_runtime.h>

// ---------------- common helpers ----------------
typedef unsigned short ushortT;
typedef unsigned int uint32;
typedef __attribute__((ext_vector_type(8))) short short8;
typedef __attribute__((ext_vector_type(4))) float f32x4;

__device__ __forceinline__ ushortT f2bf(float f) {
    uint32 u = __float_as_uint(f);
    uint32 r = (u + 0x7fffu + ((u >> 16) & 1u)) >> 16;
    return (ushortT)r;
}
__device__ __forceinline__ float bf2f(uint32 v) {
    return __uint_as_float(v << 16);
}

__device__ __forceinline__ void unpack8(uint4 v, float* f) {
    f[0] = bf2f(v.x & 0xffffu); f[1] = bf2f(v.x >> 16);
    f[2] = bf2f(v.y & 0xffffu); f[3] = bf2f(v.y >> 16);
    f[4] = bf2f(v.z & 0xffffu); f[5] = bf2f(v.z >> 16);
    f[6] = bf2f(v.w & 0xffffu); f[7] = bf2f(v.w >> 16);
}

// async global->LDS, 16B per lane. LDS dest must be wave-uniform base;
// HW writes lane i at base + i*16.
typedef __attribute__((address_space(1))) const void gvoid;
typedef __attribute__((address_space(3))) void lvoid;
__device__ __forceinline__ void gld16(const ushortT* g, ushortT* l) {
    __builtin_amdgcn_global_load_lds((gvoid*)g, (lvoid*)l, 16, 0, 0);
}

// ---------------- fp32 -> bf16 convert (vectorized) ----------------
__global__ __launch_bounds__(256) void f32_to_bf16_kernel(
    const float* __restrict__ src, ushortT* __restrict__ dst, int n4)
{
    int i = blockIdx.x * 256 + threadIdx.x;
    if (i < n4) {
        float4 v = reinterpret_cast<const float4*>(src)[i];
        ushort4 o;
        o.x = f2bf(v.x); o.y = f2bf(v.y); o.z = f2bf(v.z); o.w = f2bf(v.w);
        reinterpret_cast<ushort4*>(dst)[i] = o;
    }
}

// ---------------- pack q/k/v biases into one 3072-float buffer ----------------
__global__ __launch_bounds__(256) void pack_bias_kernel(
    const float* __restrict__ bq, const float* __restrict__ bk,
    const float* __restrict__ bv, float* __restrict__ out)
{
    int i = blockIdx.x * 256 + threadIdx.x;   // 3072
    float v = (i < 1024) ? bq[i] : (i < 2048 ? bk[i - 1024] : bv[i - 2048]);
    out[i] = v;
}

// ---------------- RoPE cos/sin table: [T][16] float2 ----------------
__global__ __launch_bounds__(256) void rope_table_kernel(float2* __restrict__ tab)
{
    int idx = blockIdx.x * 256 + threadIdx.x;   // T*16 = 131072 entries
    int t = idx >> 4;
    int i = idx & 15;
    float inv = powf(10000.0f, -(float)i / 16.0f);
    float ang = (float)t * inv;
    tab[idx] = make_float2(cosf(ang), sinf(ang));
}

// ---------------- 256x256 deep-pipelined bf16 MFMA GEMM ----------------
// C = A(MxK) * W(NxK)^T + bias.  BK=32, 4 LDS buffers, 8 waves (2m x 4n).
// Schedule per K-tile (2 phases), counted vmcnt, raw barriers, setprio,
// LDS XOR swizzle both-sides. See round-2 comments; unchanged here.
//
// XCD mapping (CRITICAL): i=bid&7 selects XCD (dispatch round-robin),
// j=bid>>3; tn=j%NTN, tm=i*16+j/NTN. All blocks sharing an A-row-panel
// (same tm) land on the SAME XCD -> A panel fetched from HBM once,
// served from that XCD's L2 thereafter. Requires M/256==128 (=8*16).
//
// MODE 2: fp32 out, no rope (final projection), NTN=4
// MODE 3: fused qkv, NTN=12. Block-uniform proj = n0>>10:
//   proj 0 (q): rope -> bf16 at Cb + row*1024 + dcol
//   proj 1/2 (k/v): fp32 present (pre-rope) at Cf + (proj-1)*MC, + rope bf16

__device__ __forceinline__ short8 ldsfrag(const ushortT* region, int row, int g) {
    int e = (row << 5) + (g << 3);
    e ^= ((row >> 1) & 3) << 3;
    return *reinterpret_cast<const short8*>(region + e);
}

#define MC_ ((size_t)33554432)   // 32768 * 1024

template<int MODE, int NTN>
__global__ __launch_bounds__(512, 2) void gemm256_kernel(
    const ushortT* __restrict__ A,   // M x K bf16
    const ushortT* __restrict__ W,   // N x K bf16 (row-major = B^T)
    const float*   __restrict__ bias,
    const float2*  __restrict__ tab, // rope table [T][16]
    ushortT*       __restrict__ Cb,  // MODE3: qlin (klin=+MC, vlin=+2MC)
    float*         __restrict__ Cf,  // MODE3: presK (presV=+MC); MODE2: MxN fp32
    int M, int N, int K)
{
    extern __shared__ ushortT lds[];   // 4 bufs x (A 8192 + B 8192) elems = 128 KB
    const int tid  = threadIdx.x;
    const int lane = tid & 63;
    const int wv   = tid >> 6;        // 0..7
    const int wm   = wv >> 2;         // 0..1  (wave row: 128 rows)
    const int wn   = wv & 3;          // 0..3  (wave col: 64 cols)
    const int g    = lane >> 4;       // k sub-block 0..3
    const int rsel = lane & 15;

    // XCD co-location swizzle (see header comment)
    const int bid = blockIdx.x;
    const int xi  = bid & 7;
    const int j   = bid >> 3;
    const int tn  = j % NTN;
    const int tm  = xi * 16 + j / NTN;
    const int m0  = tm * 256, n0 = tn * 256;

    // staging source: chunk c=tid -> row c>>2, col8 = (c&3)^((c>>3)&3)
    // (pre-swizzled global source; LDS dest stays linear: lane*16B)
    const int crow = tid >> 2;
    const int ccol = ((tid & 3) ^ ((tid >> 3) & 3)) * 8;
    const ushortT* gA0 = A + (size_t)(m0 + crow) * K + ccol;
    const ushortT* gA1 = gA0 + (size_t)128 * K;   // chunks tid+512 = rows +128
    const ushortT* gB0 = W + (size_t)(n0 + crow) * K + ccol;
    const ushortT* gB1 = gB0 + (size_t)128 * K;

    // wave-uniform LDS dest bases (element offsets within a region)
    const int dst0 = wv * 512;          // chunks tid
    const int dst1 = 4096 + wv * 512;   // chunks tid+512

    // prologue: stage tiles 0,1,2 (12 loads), wait for tile 0 (<=8 outstanding)
    #pragma unroll
    for (int t = 0; t < 3; ++t) {
        ushortT* ra = lds + t * 16384;
        ushortT* rb = ra + 8192;
        gld16(gA0 + t * 32, ra + dst0);
        gld16(gA1 + t * 32, ra + dst1);
        gld16(gB0 + t * 32, rb + dst0);
        gld16(gB1 + t * 32, rb + dst1);
    }
    asm volatile("s_waitcnt vmcnt(8)" ::: "memory");
    __builtin_amdgcn_s_barrier();

    f32x4 acc[8][4] = {};
    const int NT = K >> 5;   // 32 K-tiles

    #pragma unroll 1
    for (int t = 0; t < NT; ++t) {
        const ushortT* ra = lds + (t & 3) * 16384;
        const ushortT* rb = ra + 8192;

        // ---------- phase A ----------
        short8 Bf[4], Af[4];
        #pragma unroll
        for (int fn = 0; fn < 4; ++fn) Bf[fn] = ldsfrag(rb, wn * 64 + fn * 16 + rsel, g);
        #pragma unroll
        for (int fm = 0; fm < 4; ++fm) Af[fm] = ldsfrag(ra, wm * 128 + fm * 16 + rsel, g);
        if (t + 3 < NT) {
            ushortT* wa = lds + ((t + 3) & 3) * 16384;
            gld16(gA0 + (t + 3) * 32, wa + dst0);
            gld16(gA1 + (t + 3) * 32, wa + dst1);
        }
        asm volatile("" ::: "memory");
        __builtin_amdgcn_s_barrier();
        asm volatile("s_waitcnt lgkmcnt(0)" ::: "memory");
        __builtin_amdgcn_sched_barrier(0);
        __builtin_amdgcn_s_setprio(1);
        #pragma unroll
        for (int fm = 0; fm < 4; ++fm)
            #pragma unroll
            for (int fn = 0; fn < 4; ++fn)
                acc[fm][fn] = __builtin_amdgcn_mfma_f32_16x16x32_bf16(Af[fm], Bf[fn], acc[fm][fn], 0, 0, 0);
        __builtin_amdgcn_s_setprio(0);
        asm volatile("" ::: "memory");
        __builtin_amdgcn_s_barrier();

        // ---------- phase B ----------
        #pragma unroll
        for (int fm = 0; fm < 4; ++fm) Af[fm] = ldsfrag(ra, wm * 128 + 64 + fm * 16 + rsel, g);
        if (t + 3 < NT) {
            ushortT* wb = lds + ((t + 3) & 3) * 16384 + 8192;
            gld16(gB0 + (t + 3) * 32, wb + dst0);
            gld16(gB1 + (t + 3) * 32, wb + dst1);
        }
        if (t < NT - 3)      { asm volatile("s_waitcnt vmcnt(8)" ::: "memory"); }
        else if (t == NT - 3){ asm volatile("s_waitcnt vmcnt(4)" ::: "memory"); }
        else if (t == NT - 2){ asm volatile("s_waitcnt vmcnt(0)" ::: "memory"); }
        asm volatile("" ::: "memory");
        __builtin_amdgcn_s_barrier();
        asm volatile("s_waitcnt lgkmcnt(0)" ::: "memory");
        __builtin_amdgcn_sched_barrier(0);
        __builtin_amdgcn_s_setprio(1);
        #pragma unroll
        for (int fm = 0; fm < 4; ++fm)
            #pragma unroll
            for (int fn = 0; fn < 4; ++fn)
                acc[4 + fm][fn] = __builtin_amdgcn_mfma_f32_16x16x32_bf16(Af[fm], Bf[fn], acc[4 + fm][fn], 0, 0, 0);
        __builtin_amdgcn_s_setprio(0);
        asm volatile("" ::: "memory");
        __builtin_amdgcn_s_barrier();
    }

    // epilogue: C/D layout col = rsel, row = g*4 + e (within 16x16 frag)
    const int proj = n0 >> 10;          // MODE3: 0=q, 1=k, 2=v (block-uniform)
    #pragma unroll
    for (int fn = 0; fn < 4; ++fn) {
        const int colb = n0 + wn * 64 + fn * 16 + rsel;
        const int dcol = colb & 1023;
        const int d    = colb & 63;
        const float bv = bias[colb];
        #pragma unroll
        for (int am = 0; am < 8; ++am) {
            const int rowbase = m0 + wm * 128 + am * 16 + g * 4;
            #pragma unroll
            for (int e = 0; e < 4; ++e) {
                const int row = rowbase + e;
                const float val = acc[am][fn][e] + bv;
                if (MODE == 2) {
                    Cf[(size_t)row * N + colb] = val;
                } else {
                    if (proj != 0) {
                        // present: (B, H, T, 64) fp32, pre-rope
                        const int b = row >> 13, t = row & 8191;
                        const int h = dcol >> 6;
                        Cf[(size_t)(proj - 1) * MC_ +
                           (((size_t)b * 16 + h) * 8192 + t) * 64 + d] = val;
                    }
                    // rope: pair (d, d^1) sits at lane^1, same row
                    const float pv = __shfl_xor(val, 1, 64);
                    float ov = val;
                    if (d < 32) {
                        const int t = row & 8191;
                        const float2 cs = tab[t * 16 + (d >> 1)];
                        ov = (d & 1) ? fmaf(val, cs.x,  pv * cs.y)
                                     : fmaf(val, cs.x, -pv * cs.y);
                    }
                    Cb[(size_t)proj * MC_ + (size_t)row * 1024 + dcol] = f2bf(ov);
                }
            }
        }
    }
}

// ---------------- neighborhood attention ----------------
// wave = 8 queries x 8 dim-chunks; lane = tloc*8 + c  (8 consecutive lanes
// cover one contiguous 128B row segment). q/k/v already roped.
__global__ __launch_bounds__(256) void natt_kernel(
    const ushortT* __restrict__ Q,
    const ushortT* __restrict__ Kl,
    const ushortT* __restrict__ Vl,
    ushortT*       __restrict__ O)
{
    const int T = 8192;
    const int tid  = threadIdx.x;
    const int lane = tid & 63;
    const int tloc = lane >> 3;
    const int c    = lane & 7;

    const int wq   = (blockIdx.x * 256 + tid) >> 6;  // wave-group id
    const int qidx = wq * 8 + tloc;
    const int t = qidx & (T - 1);
    const int h = (qidx >> 13) & 15;
    const int b = qidx >> 17;

    const int shifts[4] = {0, 2, 3, 4};
    const int sh = shifts[h >> 2];
    const int dd = 1 << sh;

    const int r  = t & (dd - 1);
    const int p  = t >> sh;
    const int Lr = ((T - 1 - r) >> sh) + 1;
    int s = p - 3;
    const int smax = Lr - 7;
    s = s < 0 ? 0 : (s > smax ? smax : s);
    const int tbase = r + (s << sh);

    const size_t qoff = ((size_t)(b * T + t)) * 1024 + h * 64 + c * 8;
    float qf[8];
    unpack8(*reinterpret_cast<const uint4*>(Q + qoff), qf);

    const size_t cbase = ((size_t)b * T) * 1024 + h * 64 + c * 8;

    float sc[7];
    #pragma unroll
    for (int j = 0; j < 7; ++j) {
        const int tj = tbase + (j << sh);
        float kf[8];
        unpack8(*reinterpret_cast<const uint4*>(Kl + cbase + (size_t)tj * 1024), kf);
        float pp = 0.f;
        #pragma unroll
        for (int i = 0; i < 8; ++i) pp = fmaf(qf[i], kf[i], pp);
        pp += __shfl_xor(pp, 1, 64);
        pp += __shfl_xor(pp, 2, 64);
        pp += __shfl_xor(pp, 4, 64);
        sc[j] = pp;
    }

    float mx = sc[0];
    #pragma unroll
    for (int j = 1; j < 7; ++j) mx = fmaxf(mx, sc[j]);
    float den = 0.f;
    #pragma unroll
    for (int j = 0; j < 7; ++j) { sc[j] = __expf(sc[j] - mx); den += sc[j]; }
    const float inv = 1.0f / den;

    float out[8] = {};
    #pragma unroll
    for (int j = 0; j < 7; ++j) {
        const int tj = tbase + (j << sh);
        float vf[8];
        unpack8(*reinterpret_cast<const uint4*>(Vl + cbase + (size_t)tj * 1024), vf);
        #pragma unroll
        for (int i = 0; i < 8; ++i) out[i] = fmaf(sc[j], vf[i], out[i]);
    }

    short8 ov;
    #pragma unroll
    for (int i = 0; i < 8; ++i) ov[i] = (short)f2bf(out[i] * inv);
    *reinterpret_cast<short8*>(const_cast<ushortT*>(O + qoff)) = ov;
}

// ---------------- launcher ----------------
extern "C" void kernel_launch(void* const* d_in, const int* in_sizes, int n_in,
                              void* d_out, int out_size, void* d_ws, size_t ws_size,
                              hipStream_t stream)
{
    const float* x  = (const float*)d_in[0];
    const float* wq = (const float*)d_in[1];
    const float* bq = (const float*)d_in[2];
    const float* wk = (const float*)d_in[3];
    const float* bk = (const float*)d_in[4];
    const float* wv = (const float*)d_in[5];
    const float* bv = (const float*)d_in[6];
    const float* wp = (const float*)d_in[7];
    const float* bp = (const float*)d_in[8];

    const int B = 4, T = 8192, C = 1024;
    const int M = B * T;                    // 32768
    const size_t MC = (size_t)M * C;        // 33,554,432

    char* ws = (char*)d_ws;
    ushortT* xb    = (ushortT*)ws;                                  // 64MB (reused as attn out)
    ushortT* wqkvb = (ushortT*)(ws + (size_t)64 * 1024 * 1024);     // 6MB packed [wq;wk;wv]
    ushortT* wpb   = wqkvb + (size_t)3 * C * C;                     // 2MB
    ushortT* qlin  = (ushortT*)(ws + (size_t)72 * 1024 * 1024);     // 64MB (klin,vlin follow)
    ushortT* klin  = qlin + MC;
    ushortT* vlin  = klin + MC;
    float2*  tab   = (float2*)(ws + (size_t)264 * 1024 * 1024);     // 1MB
    float*   bqkv  = (float*)(ws + (size_t)266 * 1024 * 1024);      // 12KB

    float* y     = (float*)d_out;
    float* presK = y + MC;                  // presV = presK + MC (contiguous)

    // allow 128 KB dynamic LDS on the GEMM instantiations (idempotent)
    hipFuncSetAttribute((const void*)gemm256_kernel<3, 12>,
                        hipFuncAttributeMaxDynamicSharedMemorySize, 131072);
    hipFuncSetAttribute((const void*)gemm256_kernel<2, 4>,
                        hipFuncAttributeMaxDynamicSharedMemorySize, 131072);

    rope_table_kernel<<<512, 256, 0, stream>>>(tab);
    pack_bias_kernel<<<12, 256, 0, stream>>>(bq, bk, bv, bqkv);

    f32_to_bf16_kernel<<<(int)(MC / 4 / 256), 256, 0, stream>>>(x, xb, (int)(MC / 4));
    const int wn4 = C * C / 4;
    f32_to_bf16_kernel<<<(wn4 + 255) / 256, 256, 0, stream>>>(wq, wqkvb, wn4);
    f32_to_bf16_kernel<<<(wn4 + 255) / 256, 256, 0, stream>>>(wk, wqkvb + (size_t)C * C, wn4);
    f32_to_bf16_kernel<<<(wn4 + 255) / 256, 256, 0, stream>>>(wv, wqkvb + (size_t)2 * C * C, wn4);
    f32_to_bf16_kernel<<<(wn4 + 255) / 256, 256, 0, stream>>>(wp, wpb, wn4);

    // fused qkv: N = 3072, nwg = 128 * 12 = 1536
    gemm256_kernel<3, 12><<<1536, 512, 131072, stream>>>(
        xb, wqkvb, bqkv, tab, qlin, presK, M, 3 * C, C);

    natt_kernel<<<(B * 16 * T) / 32, 256, 0, stream>>>(qlin, klin, vlin, xb);

    // output projection: N = 1024, nwg = 128 * 4 = 512
    gemm256_kernel<2, 4><<<512, 512, 131072, stream>>>(
        xb, wpb, bp, tab, nullptr, y, M, C, C);
}

// Round 5
// 583.072 us; speedup vs baseline: 1.1168x; 1.1168x over previous
//
#include <hip/hip_runtime.h>

// ---------------- common helpers ----------------
typedef unsigned short ushortT;
typedef unsigned int uint32;
typedef __attribute__((ext_vector_type(8))) short short8;
typedef __attribute__((ext_vector_type(4))) float f32x4;

__device__ __forceinline__ ushortT f2bf(float f) {
    uint32 u = __float_as_uint(f);
    uint32 r = (u + 0x7fffu + ((u >> 16) & 1u)) >> 16;
    return (ushortT)r;
}
__device__ __forceinline__ float bf2f(uint32 v) {
    return __uint_as_float(v << 16);
}

__device__ __forceinline__ void unpack8(uint4 v, float* f) {
    f[0] = bf2f(v.x & 0xffffu); f[1] = bf2f(v.x >> 16);
    f[2] = bf2f(v.y & 0xffffu); f[3] = bf2f(v.y >> 16);
    f[4] = bf2f(v.z & 0xffffu); f[5] = bf2f(v.z >> 16);
    f[6] = bf2f(v.w & 0xffffu); f[7] = bf2f(v.w >> 16);
}

// async global->LDS, 16B per lane. LDS dest must be wave-uniform base;
// HW writes lane i at base + i*16.
typedef __attribute__((address_space(1))) const void gvoid;
typedef __attribute__((address_space(3))) void lvoid;
__device__ __forceinline__ void gld16(const ushortT* g, ushortT* l) {
    __builtin_amdgcn_global_load_lds((gvoid*)g, (lvoid*)l, 16, 0, 0);
}

// ---------------- fp32 -> bf16 convert (vectorized) ----------------
__global__ __launch_bounds__(256) void f32_to_bf16_kernel(
    const float* __restrict__ src, ushortT* __restrict__ dst, int n4)
{
    int i = blockIdx.x * 256 + threadIdx.x;
    if (i < n4) {
        float4 v = reinterpret_cast<const float4*>(src)[i];
        ushort4 o;
        o.x = f2bf(v.x); o.y = f2bf(v.y); o.z = f2bf(v.z); o.w = f2bf(v.w);
        reinterpret_cast<ushort4*>(dst)[i] = o;
    }
}

// ---------------- RoPE cos/sin table: [T][16] float2 ----------------
__global__ __launch_bounds__(256) void rope_table_kernel(float2* __restrict__ tab)
{
    int idx = blockIdx.x * 256 + threadIdx.x;   // T*16 = 131072 entries
    int t = idx >> 4;
    int i = idx & 15;
    float inv = powf(10000.0f, -(float)i / 16.0f);
    float ang = (float)t * inv;
    tab[idx] = make_float2(cosf(ang), sinf(ang));
}

// ---------------- 256x256 deep-pipelined bf16 MFMA GEMM ----------------
// C = A(MxK) * W(NxK)^T + bias.  BK=32, 4 LDS buffers, 8 waves (2m x 4n).
// Schedule per K-tile (2 phases), counted vmcnt, raw barriers, setprio,
// LDS XOR swizzle both-sides.
//
// XCD mapping: i=bid&7 selects XCD (dispatch round-robin), j=bid>>3;
// tn=j%NTN, tm=xi*16+j/NTN. All blocks sharing an A-row-panel (same tm)
// land on the SAME XCD -> A panel fetched from HBM once, L2-served after.
// Proven: r4 p-GEMM hit ~1045 TF with this mapping.
// UNFUSED on purpose: W must stay <= ~2MB so A-panel + W fit per-XCD 4MB L2
// (r4 post-mortem: fused N=3072 W=6MB thrashed L2 -> 18% MfmaUtil).
//
// MODE 0: rope -> bf16 out (q)
// MODE 1: fp32 "present" out (pre-rope, (B,H,T,64)) + rope -> bf16 out (k,v)
// MODE 2: fp32 out, no rope (final projection)

__device__ __forceinline__ short8 ldsfrag(const ushortT* region, int row, int g) {
    int e = (row << 5) + (g << 3);
    e ^= ((row >> 1) & 3) << 3;
    return *reinterpret_cast<const short8*>(region + e);
}

template<int MODE, int NTN>
__global__ __launch_bounds__(512, 2) void gemm256_kernel(
    const ushortT* __restrict__ A,   // M x K bf16
    const ushortT* __restrict__ W,   // N x K bf16 (row-major = B^T)
    const float*   __restrict__ bias,
    const float2*  __restrict__ tab, // rope table [T][16]
    ushortT*       __restrict__ Cb,  // M x N bf16 (modes 0,1)
    float*         __restrict__ Cf,  // mode1: present base; mode2: M x N fp32
    int M, int N, int K)
{
    extern __shared__ ushortT lds[];   // 4 bufs x (A 8192 + B 8192) elems = 128 KB
    const int tid  = threadIdx.x;
    const int lane = tid & 63;
    const int wv   = tid >> 6;        // 0..7
    const int wm   = wv >> 2;         // 0..1  (wave row: 128 rows)
    const int wn   = wv & 3;          // 0..3  (wave col: 64 cols)
    const int g    = lane >> 4;       // k sub-block 0..3
    const int rsel = lane & 15;

    // XCD co-location swizzle (see header comment)
    const int bid = blockIdx.x;
    const int xi  = bid & 7;
    const int j   = bid >> 3;
    const int tn  = j % NTN;
    const int tm  = xi * 16 + j / NTN;
    const int m0  = tm * 256, n0 = tn * 256;

    // staging source: chunk c=tid -> row c>>2, col8 = (c&3)^((c>>3)&3)
    // (pre-swizzled global source; LDS dest stays linear: lane*16B)
    const int crow = tid >> 2;
    const int ccol = ((tid & 3) ^ ((tid >> 3) & 3)) * 8;
    const ushortT* gA0 = A + (size_t)(m0 + crow) * K + ccol;
    const ushortT* gA1 = gA0 + (size_t)128 * K;   // chunks tid+512 = rows +128
    const ushortT* gB0 = W + (size_t)(n0 + crow) * K + ccol;
    const ushortT* gB1 = gB0 + (size_t)128 * K;

    // wave-uniform LDS dest bases (element offsets within a region)
    const int dst0 = wv * 512;          // chunks tid
    const int dst1 = 4096 + wv * 512;   // chunks tid+512

    // prologue: stage tiles 0,1,2 (12 loads), wait for tile 0 (<=8 outstanding)
    #pragma unroll
    for (int t = 0; t < 3; ++t) {
        ushortT* ra = lds + t * 16384;
        ushortT* rb = ra + 8192;
        gld16(gA0 + t * 32, ra + dst0);
        gld16(gA1 + t * 32, ra + dst1);
        gld16(gB0 + t * 32, rb + dst0);
        gld16(gB1 + t * 32, rb + dst1);
    }
    asm volatile("s_waitcnt vmcnt(8)" ::: "memory");
    __builtin_amdgcn_s_barrier();

    f32x4 acc[8][4] = {};
    const int NT = K >> 5;   // 32 K-tiles

    #pragma unroll 1
    for (int t = 0; t < NT; ++t) {
        const ushortT* ra = lds + (t & 3) * 16384;
        const ushortT* rb = ra + 8192;

        // ---------- phase A ----------
        short8 Bf[4], Af[4];
        #pragma unroll
        for (int fn = 0; fn < 4; ++fn) Bf[fn] = ldsfrag(rb, wn * 64 + fn * 16 + rsel, g);
        #pragma unroll
        for (int fm = 0; fm < 4; ++fm) Af[fm] = ldsfrag(ra, wm * 128 + fm * 16 + rsel, g);
        if (t + 3 < NT) {
            ushortT* wa = lds + ((t + 3) & 3) * 16384;
            gld16(gA0 + (t + 3) * 32, wa + dst0);
            gld16(gA1 + (t + 3) * 32, wa + dst1);
        }
        asm volatile("" ::: "memory");
        __builtin_amdgcn_s_barrier();
        asm volatile("s_waitcnt lgkmcnt(0)" ::: "memory");
        __builtin_amdgcn_sched_barrier(0);
        __builtin_amdgcn_s_setprio(1);
        #pragma unroll
        for (int fm = 0; fm < 4; ++fm)
            #pragma unroll
            for (int fn = 0; fn < 4; ++fn)
                acc[fm][fn] = __builtin_amdgcn_mfma_f32_16x16x32_bf16(Af[fm], Bf[fn], acc[fm][fn], 0, 0, 0);
        __builtin_amdgcn_s_setprio(0);
        asm volatile("" ::: "memory");
        __builtin_amdgcn_s_barrier();

        // ---------- phase B ----------
        #pragma unroll
        for (int fm = 0; fm < 4; ++fm) Af[fm] = ldsfrag(ra, wm * 128 + 64 + fm * 16 + rsel, g);
        if (t + 3 < NT) {
            ushortT* wb = lds + ((t + 3) & 3) * 16384 + 8192;
            gld16(gB0 + (t + 3) * 32, wb + dst0);
            gld16(gB1 + (t + 3) * 32, wb + dst1);
        }
        if (t < NT - 3)      { asm volatile("s_waitcnt vmcnt(8)" ::: "memory"); }
        else if (t == NT - 3){ asm volatile("s_waitcnt vmcnt(4)" ::: "memory"); }
        else if (t == NT - 2){ asm volatile("s_waitcnt vmcnt(0)" ::: "memory"); }
        asm volatile("" ::: "memory");
        __builtin_amdgcn_s_barrier();
        asm volatile("s_waitcnt lgkmcnt(0)" ::: "memory");
        __builtin_amdgcn_sched_barrier(0);
        __builtin_amdgcn_s_setprio(1);
        #pragma unroll
        for (int fm = 0; fm < 4; ++fm)
            #pragma unroll
            for (int fn = 0; fn < 4; ++fn)
                acc[4 + fm][fn] = __builtin_amdgcn_mfma_f32_16x16x32_bf16(Af[fm], Bf[fn], acc[4 + fm][fn], 0, 0, 0);
        __builtin_amdgcn_s_setprio(0);
        asm volatile("" ::: "memory");
        __builtin_amdgcn_s_barrier();
    }

    // epilogue: C/D layout col = rsel, row = g*4 + e (within 16x16 frag)
    #pragma unroll
    for (int fn = 0; fn < 4; ++fn) {
        const int colb = n0 + wn * 64 + fn * 16 + rsel;
        const int d    = colb & 63;
        const float bv = bias[colb];
        #pragma unroll
        for (int am = 0; am < 8; ++am) {
            const int rowbase = m0 + wm * 128 + am * 16 + g * 4;
            #pragma unroll
            for (int e = 0; e < 4; ++e) {
                const int row = rowbase + e;
                const float val = acc[am][fn][e] + bv;
                if (MODE == 1) {
                    // present: (B, H, T, 64) fp32, pre-rope
                    const int b = row >> 13, t = row & 8191;
                    const int h = colb >> 6;
                    Cf[(((size_t)b * 16 + h) * 8192 + t) * 64 + d] = val;
                }
                if (MODE == 2) {
                    Cf[(size_t)row * N + colb] = val;
                } else {
                    // rope: pair (d, d^1) sits at lane^1, same row
                    const float pv = __shfl_xor(val, 1, 64);
                    float ov = val;
                    if (d < 32) {
                        const int t = row & 8191;
                        const float2 cs = tab[t * 16 + (d >> 1)];
                        ov = (d & 1) ? fmaf(val, cs.x,  pv * cs.y)
                                     : fmaf(val, cs.x, -pv * cs.y);
                    }
                    Cb[(size_t)row * N + colb] = f2bf(ov);
                }
            }
        }
    }
}

// ---------------- neighborhood attention ----------------
// wave = 8 queries x 8 dim-chunks; lane = tloc*8 + c  (8 consecutive lanes
// cover one contiguous 128B row segment). q/k/v already roped.
__global__ __launch_bounds__(256) void natt_kernel(
    const ushortT* __restrict__ Q,
    const ushortT* __restrict__ Kl,
    const ushortT* __restrict__ Vl,
    ushortT*       __restrict__ O)
{
    const int T = 8192;
    const int tid  = threadIdx.x;
    const int lane = tid & 63;
    const int tloc = lane >> 3;
    const int c    = lane & 7;

    const int wq   = (blockIdx.x * 256 + tid) >> 6;  // wave-group id
    const int qidx = wq * 8 + tloc;
    const int t = qidx & (T - 1);
    const int h = (qidx >> 13) & 15;
    const int b = qidx >> 17;

    const int shifts[4] = {0, 2, 3, 4};
    const int sh = shifts[h >> 2];
    const int dd = 1 << sh;

    const int r  = t & (dd - 1);
    const int p  = t >> sh;
    const int Lr = ((T - 1 - r) >> sh) + 1;
    int s = p - 3;
    const int smax = Lr - 7;
    s = s < 0 ? 0 : (s > smax ? smax : s);
    const int tbase = r + (s << sh);

    const size_t qoff = ((size_t)(b * T + t)) * 1024 + h * 64 + c * 8;
    float qf[8];
    unpack8(*reinterpret_cast<const uint4*>(Q + qoff), qf);

    const size_t cbase = ((size_t)b * T) * 1024 + h * 64 + c * 8;

    float sc[7];
    #pragma unroll
    for (int j = 0; j < 7; ++j) {
        const int tj = tbase + (j << sh);
        float kf[8];
        unpack8(*reinterpret_cast<const uint4*>(Kl + cbase + (size_t)tj * 1024), kf);
        float pp = 0.f;
        #pragma unroll
        for (int i = 0; i < 8; ++i) pp = fmaf(qf[i], kf[i], pp);
        pp += __shfl_xor(pp, 1, 64);
        pp += __shfl_xor(pp, 2, 64);
        pp += __shfl_xor(pp, 4, 64);
        sc[j] = pp;
    }

    float mx = sc[0];
    #pragma unroll
    for (int j = 1; j < 7; ++j) mx = fmaxf(mx, sc[j]);
    float den = 0.f;
    #pragma unroll
    for (int j = 0; j < 7; ++j) { sc[j] = __expf(sc[j] - mx); den += sc[j]; }
    const float inv = 1.0f / den;

    float out[8] = {};
    #pragma unroll
    for (int j = 0; j < 7; ++j) {
        const int tj = tbase + (j << sh);
        float vf[8];
        unpack8(*reinterpret_cast<const uint4*>(Vl + cbase + (size_t)tj * 1024), vf);
        #pragma unroll
        for (int i = 0; i < 8; ++i) out[i] = fmaf(sc[j], vf[i], out[i]);
    }

    short8 ov;
    #pragma unroll
    for (int i = 0; i < 8; ++i) ov[i] = (short)f2bf(out[i] * inv);
    *reinterpret_cast<short8*>(const_cast<ushortT*>(O + qoff)) = ov;
}

// ---------------- launcher ----------------
extern "C" void kernel_launch(void* const* d_in, const int* in_sizes, int n_in,
                              void* d_out, int out_size, void* d_ws, size_t ws_size,
                              hipStream_t stream)
{
    const float* x  = (const float*)d_in[0];
    const float* wq = (const float*)d_in[1];
    const float* bq = (const float*)d_in[2];
    const float* wk = (const float*)d_in[3];
    const float* bk = (const float*)d_in[4];
    const float* wv = (const float*)d_in[5];
    const float* bv = (const float*)d_in[6];
    const float* wp = (const float*)d_in[7];
    const float* bp = (const float*)d_in[8];

    const int B = 4, T = 8192, C = 1024;
    const int M = B * T;                    // 32768
    const size_t MC = (size_t)M * C;        // 33,554,432

    char* ws = (char*)d_ws;
    ushortT* xb   = (ushortT*)ws;                                   // 64MB (reused as attn out)
    ushortT* wqb  = (ushortT*)(ws + (size_t)64 * 1024 * 1024);
    ushortT* wkb  = wqb + (size_t)C * C;
    ushortT* wvb  = wkb + (size_t)C * C;
    ushortT* wpb  = wvb + (size_t)C * C;
    ushortT* qlin = (ushortT*)(ws + (size_t)72 * 1024 * 1024);      // 64MB
    ushortT* klin = qlin + MC;                                      // 64MB
    ushortT* vlin = klin + MC;                                      // 64MB
    float2*  tab  = (float2*)(ws + (size_t)264 * 1024 * 1024);      // 1MB

    float* y     = (float*)d_out;
    float* presK = y + MC;
    float* presV = presK + MC;

    // allow 128 KB dynamic LDS on the GEMM instantiations (idempotent)
    hipFuncSetAttribute((const void*)gemm256_kernel<0, 4>,
                        hipFuncAttributeMaxDynamicSharedMemorySize, 131072);
    hipFuncSetAttribute((const void*)gemm256_kernel<1, 4>,
                        hipFuncAttributeMaxDynamicSharedMemorySize, 131072);
    hipFuncSetAttribute((const void*)gemm256_kernel<2, 4>,
                        hipFuncAttributeMaxDynamicSharedMemorySize, 131072);

    rope_table_kernel<<<512, 256, 0, stream>>>(tab);

    f32_to_bf16_kernel<<<(int)(MC / 4 / 256), 256, 0, stream>>>(x, xb, (int)(MC / 4));
    const int wn4 = C * C / 4;
    f32_to_bf16_kernel<<<(wn4 + 255) / 256, 256, 0, stream>>>(wq, wqb, wn4);
    f32_to_bf16_kernel<<<(wn4 + 255) / 256, 256, 0, stream>>>(wk, wkb, wn4);
    f32_to_bf16_kernel<<<(wn4 + 255) / 256, 256, 0, stream>>>(wv, wvb, wn4);
    f32_to_bf16_kernel<<<(wn4 + 255) / 256, 256, 0, stream>>>(wp, wpb, wn4);

    const int nwg = (M / 256) * (C / 256);   // 128*4 = 512
    gemm256_kernel<0, 4><<<nwg, 512, 131072, stream>>>(xb, wqb, bq, tab, qlin, nullptr, M, C, C);
    gemm256_kernel<1, 4><<<nwg, 512, 131072, stream>>>(xb, wkb, bk, tab, klin, presK, M, C, C);
    gemm256_kernel<1, 4><<<nwg, 512, 131072, stream>>>(xb, wvb, bv, tab, vlin, presV, M, C, C);

    natt_kernel<<<(B * 16 * T) / 32, 256, 0, stream>>>(qlin, klin, vlin, xb);

    gemm256_kernel<2, 4><<<nwg, 512, 131072, stream>>>(xb, wpb, bp, tab, nullptr, y, M, C, C);
}